// Round 6
// baseline (443.370 us; speedup 1.0000x reference)
//
#include <hip/hip_runtime.h>
#include <math.h>

#define N 1024
#define NN (N*N)
#define NE 32768

// ---------------- workspace layout (floats) ----------------
// A:    0..5NN   (att0: 2 mats, att1: 3 mats; attended in place)
// H1:   5..13NN  (conv1 out, dead after conv2). After that:
//   M0 = 5NN, Pb = 6NN, CSR = 7NN.., BT = 9NN, Pa = 10..13NN, M1 = Pa[0] = 10NN, AN = 11NN
// H2_0 = 13NN, H2_1 = 13NN+264196; scalars + XW1/HB/HW2 after
#define OFF_A    ((size_t)0)
#define OFF_H10  ((size_t)(5*NN))
#define OFF_M0   ((size_t)(5*NN))
#define OFF_PB   ((size_t)(6*NN))
#define OFF_CSR  ((size_t)(7*NN))
#define OFF_BT   ((size_t)(9*NN))
#define OFF_PA   ((size_t)(10*NN))
#define OFF_M1   ((size_t)(10*NN))
#define OFF_AN   ((size_t)(11*NN))
#define OFF_H20  ((size_t)(13*NN))
#define OFF_H21  (OFF_H20 + 264196)
#define OFF_SC   (OFF_H21 + 264196)
// scalar vectors (1024 each)
#define SC_D0a 0
#define SC_F0a 1024
#define SC_D1a 2048
#define SC_F1a 3072
#define SC_D0b 4096
#define SC_F0b 5120
#define SC_D1b 6144
#define SC_F1b 7168
#define SC_D1c 8192
#define SC_F1c 9216
#define SC_D2  10240
#define SC_F2  11264
#define OFF_XW1  (OFF_SC + 12288)
#define OFF_HB   (OFF_XW1 + 65536)
#define OFF_HW2  (OFF_HB + 65536)

#define CSR_STRIDE 96

// ---------------- edge scatter (all 5 edge sets, one launch) ----------------
__global__ void k_scatter5(const int* __restrict__ e0, const int* __restrict__ e1,
                           const int* __restrict__ e2, const int* __restrict__ e3,
                           const int* __restrict__ e4, float* __restrict__ A) {
  int g = blockIdx.x * 256 + threadIdx.x;
  int seg = g >> 15;
  int k = g & 32767;
  const int* e = (seg == 0) ? e0 : (seg == 1) ? e1 : (seg == 2) ? e2 : (seg == 3) ? e3 : e4;
  atomicAdd(&A[(size_t)seg * NN + (size_t)e[k] * N + e[NE + k]], 1.0f);
}

// ---------------- conv1 (pad=1) + relu + maxpool2, both blocks in one dispatch ----------------
template<int L>
__device__ __forceinline__ void conv1_body(const float* __restrict__ A,
    const float* __restrict__ W, const float* __restrict__ Bn, float* __restrict__ out) {
  __shared__ float sIn[L][34][35];
  __shared__ float sW[16 * L * 9];
  __shared__ float sB[16];
  int tid = threadIdx.y * 16 + threadIdx.x;
  for (int i = tid; i < 16 * L * 9; i += 256) sW[i] = W[i];
  if (tid < 16) sB[tid] = Bn[tid];
  const int x0 = blockIdx.x * 32 - 1;
  const int y0 = blockIdx.y * 32 - 1;
  for (int idx = tid; idx < L * 34 * 34; idx += 256) {
    int l = idx / (34 * 34);
    int rem = idx - l * 34 * 34;
    int r = rem / 34, c = rem - r * 34;
    int iy = y0 + r, ix = x0 + c;
    sIn[l][r][c] = (iy >= 0 && iy < N && ix >= 0 && ix < N) ? A[(size_t)l * NN + (size_t)iy * N + ix] : 0.f;
  }
  __syncthreads();
  const int tx = threadIdx.x, ty = threadIdx.y;
  float p[L][4][4];
  #pragma unroll
  for (int l = 0; l < L; ++l)
    #pragma unroll
    for (int r = 0; r < 4; ++r)
      #pragma unroll
      for (int c = 0; c < 4; ++c)
        p[l][r][c] = sIn[l][2 * ty + r][2 * tx + c];
  const int ox = blockIdx.x * 16 + tx;
  const int oy = blockIdx.y * 16 + ty;
  for (int oc = 0; oc < 16; ++oc) {
    float wr[L * 9];
    #pragma unroll
    for (int t = 0; t < L * 9; ++t) wr[t] = sW[oc * L * 9 + t];
    float m = -1e30f;
    #pragma unroll
    for (int dy = 0; dy < 2; ++dy)
      #pragma unroll
      for (int dx = 0; dx < 2; ++dx) {
        float s = 0.f;
        #pragma unroll
        for (int l = 0; l < L; ++l)
          #pragma unroll
          for (int ky = 0; ky < 3; ++ky)
            #pragma unroll
            for (int kx = 0; kx < 3; ++kx)
              s = fmaf(p[l][dy + ky][dx + kx], wr[l * 9 + ky * 3 + kx], s);
        m = fmaxf(m, s);
      }
    out[(size_t)oc * 512 * 512 + (size_t)oy * 512 + ox] = fmaxf(m + sB[oc], 0.f);
  }
}

__global__ __launch_bounds__(256) void k_conv1_both(const float* __restrict__ Ab,
    const float* __restrict__ W0, const float* __restrict__ b0,
    const float* __restrict__ W1, const float* __restrict__ b1, float* __restrict__ H1b) {
  if (blockIdx.z == 0) conv1_body<2>(Ab, W0, b0, H1b);
  else                 conv1_body<3>(Ab + 2 * NN, W1, b1, H1b + 4 * NN);
}

// ---------------- conv2 (pad=2) + relu + maxpool2, both blocks, double-buffered staging ----------------
__global__ __launch_bounds__(256) void k_conv2_both(const float* __restrict__ H1b,
    const float* __restrict__ W0, const float* __restrict__ b0,
    const float* __restrict__ W1, const float* __restrict__ b1,
    float* __restrict__ H2_0, float* __restrict__ H2_1) {
  const int z = blockIdx.z;
  const float* in = H1b + (size_t)z * 4 * NN;
  const float* W  = z ? W1 : W0;
  const float* Bn = z ? b1 : b0;
  float* out = z ? H2_1 : H2_0;
  __shared__ float sIn[2][4][36][37];
  __shared__ float sW[4 * 16 * 9];
  __shared__ float sB[4];
  int tid = threadIdx.y * 16 + threadIdx.x;
  for (int i = tid; i < 4 * 16 * 9; i += 256) sW[i] = W[i];
  if (tid < 4) sB[tid] = Bn[tid];
  const int x0 = blockIdx.x * 32 - 2;
  const int y0 = blockIdx.y * 32 - 2;
  const int tx = threadIdx.x, ty = threadIdx.y;

  auto stage = [&](int g, int buf) {
    for (int idx = tid; idx < 4 * 36 * 36; idx += 256) {
      int icl = idx / 1296;
      int rem = idx - icl * 1296;
      int r = rem / 36, c = rem - r * 36;
      int iy = y0 + r, ix = x0 + c;
      sIn[buf][icl][r][c] = (iy >= 0 && iy < 512 && ix >= 0 && ix < 512)
                            ? in[(size_t)(4 * g + icl) * 262144 + (size_t)iy * 512 + ix] : 0.f;
    }
  };

  float acc[4][2][2];
  #pragma unroll
  for (int oc = 0; oc < 4; ++oc)
    #pragma unroll
    for (int dy = 0; dy < 2; ++dy)
      #pragma unroll
      for (int dx = 0; dx < 2; ++dx) acc[oc][dy][dx] = 0.f;

  stage(0, 0);
  for (int g = 0; g < 4; ++g) {
    __syncthreads();
    if (g < 3) stage(g + 1, (g + 1) & 1);
    const int buf = g & 1;
    #pragma unroll
    for (int icl = 0; icl < 4; ++icl) {
      float p[4][4];
      #pragma unroll
      for (int r = 0; r < 4; ++r)
        #pragma unroll
        for (int c = 0; c < 4; ++c) p[r][c] = sIn[buf][icl][2 * ty + r][2 * tx + c];
      #pragma unroll
      for (int oc = 0; oc < 4; ++oc)
        #pragma unroll
        for (int ky = 0; ky < 3; ++ky)
          #pragma unroll
          for (int kx = 0; kx < 3; ++kx) {
            float w = sW[oc * 144 + (4 * g + icl) * 9 + ky * 3 + kx];
            #pragma unroll
            for (int dy = 0; dy < 2; ++dy)
              #pragma unroll
              for (int dx = 0; dx < 2; ++dx)
                acc[oc][dy][dx] = fmaf(p[dy + ky][dx + kx], w, acc[oc][dy][dx]);
          }
    }
  }
  const int ox = blockIdx.x * 16 + tx;
  const int oy = blockIdx.y * 16 + ty;
  if (ox < 257 && oy < 257) {
    #pragma unroll
    for (int oc = 0; oc < 4; ++oc) {
      float m = fmaxf(fmaxf(acc[oc][0][0], acc[oc][0][1]), fmaxf(acc[oc][1][0], acc[oc][1][1]));
      out[(size_t)oc * 66049 + (size_t)oy * 257 + ox] = fmaxf(m + sB[oc], 0.f);
    }
  }
}

// ---------------- fused tconv1+relu + tconv2+sigmoid + attended (A *= att), both blocks ----------------
__global__ __launch_bounds__(256) void k_tc_both(
    const float* __restrict__ H2_0, const float* __restrict__ H2_1,
    const float* __restrict__ t1w0, const float* __restrict__ t1b0,
    const float* __restrict__ t2w0, const float* __restrict__ t2b0,
    const float* __restrict__ t1w1, const float* __restrict__ t1b1,
    const float* __restrict__ t2w1, const float* __restrict__ t2b1,
    float* __restrict__ Ab) {
  const int z = blockIdx.z;
  const int L = 2 + z;
  const float* in  = z ? H2_1 : H2_0;
  const float* W1p = z ? t1w1 : t1w0;
  const float* B1p = z ? t1b1 : t1b0;
  const float* W2p = z ? t2w1 : t2w0;
  const float* B2p = z ? t2b1 : t2b0;
  float* A = Ab + (size_t)z * 2 * NN;
  __shared__ float sW1[256], sB1[16], sW2[192], sB2[3];
  int tid = threadIdx.y * 16 + threadIdx.x;
  sW1[tid] = W1p[tid];
  if (tid < 16) sB1[tid] = B1p[tid];
  for (int i = tid; i < L * 64; i += 256) sW2[i] = W2p[i];
  if (tid < L) sB2[tid] = B2p[tid];
  __syncthreads();
  const int n = blockIdx.x * 16 + threadIdx.x;   // 0..511
  const int m = blockIdx.y * 16 + threadIdx.y;   // 0..511
  const int p = m >> 1, q = n >> 1;
  const int f1y = 1 - (m & 1), f1x = 1 - (n & 1);
  float vin[4];
  #pragma unroll
  for (int ci = 0; ci < 4; ++ci) vin[ci] = in[(size_t)ci * 66049 + (size_t)p * 257 + q];
  float v[16];
  #pragma unroll
  for (int c = 0; c < 16; ++c) {
    float s = sB1[c];
    #pragma unroll
    for (int ci = 0; ci < 4; ++ci)
      s = fmaf(vin[ci], sW1[c * 16 + ci * 4 + f1y * 2 + f1x], s);
    v[c] = fmaxf(s, 0.f);
  }
  for (int l = 0; l < L; ++l) {
    #pragma unroll
    for (int dy = 0; dy < 2; ++dy)
      #pragma unroll
      for (int dx = 0; dx < 2; ++dx) {
        float s = sB2[l];
        #pragma unroll
        for (int c = 0; c < 16; ++c)
          s = fmaf(v[c], sW2[l * 64 + c * 4 + (1 - dy) * 2 + (1 - dx)], s);
        float sg = 1.f / (1.f + expf(-s));
        size_t idx = (size_t)l * NN + (size_t)(2 * m + dy) * N + (2 * n + dx);
        A[idx] *= sg;
      }
  }
}

// ---------------- extract CSR of 4 attended matrices + deg of left mats ----------------
__global__ __launch_bounds__(256) void k_extract(const float* __restrict__ Ab,
    int* __restrict__ gcol, float* __restrict__ gval, int* __restrict__ gcnt,
    float* __restrict__ D0a, float* __restrict__ F0a,
    float* __restrict__ D1a, float* __restrict__ F1a) {
  const int row = blockIdx.x;
  const int y = blockIdx.y;                 // 0:A00 1:A01 2:A10 3:A11
  const float* base = Ab + (size_t)y * NN + (size_t)row * N;
  __shared__ int cnt;
  __shared__ float sdiag;
  __shared__ float red[4];
  if (threadIdx.x == 0) cnt = 0;
  __syncthreads();
  const int j4 = threadIdx.x;
  float4 v = ((const float4*)base)[j4];
  if (j4 == (row >> 2)) sdiag = ((const float*)&v)[row & 3];
  const size_t rb = ((size_t)y * 1024 + row) * CSR_STRIDE;
  #pragma unroll
  for (int t = 0; t < 4; ++t) {
    float x = ((const float*)&v)[t];
    if (x != 0.f) {
      int p = atomicAdd(&cnt, 1);
      if (p < CSR_STRIDE) { gcol[rb + p] = 4 * j4 + t; gval[rb + p] = x; }
    }
  }
  float s = v.x + v.y + v.z + v.w;
  #pragma unroll
  for (int o = 32; o > 0; o >>= 1) s += __shfl_down(s, o, 64);
  if ((threadIdx.x & 63) == 0) red[threadIdx.x >> 6] = s;
  __syncthreads();
  if (threadIdx.x == 0) {
    gcnt[(size_t)y * 1024 + row] = (cnt < CSR_STRIDE) ? cnt : CSR_STRIDE;
    if (y == 0 || y == 2) {
      float tot = red[0] + red[1] + red[2] + red[3];
      float fl = (sdiag == 0.f) ? 1.f : 0.f;
      float deg = tot + fl;
      float* D = (y == 0) ? D0a : D1a;
      float* F = (y == 0) ? F0a : F1a;
      D[row] = (deg > 0.f) ? (1.f / sqrtf(deg)) : 0.f;
      F[row] = fl;
    }
  }
}

// ---------------- double-sparse SpMM: C_row = [norm(left)]_row @ right, + deg epilogue ----------------
__global__ __launch_bounds__(256) void k_spmm(
    const int* __restrict__ gcol, const float* __restrict__ gval, const int* __restrict__ gcnt,
    const float* __restrict__ D0a, const float* __restrict__ F0a,
    const float* __restrict__ D1a, const float* __restrict__ F1a,
    float* __restrict__ M0, float* __restrict__ BT,
    float* __restrict__ D0b, float* __restrict__ F0b,
    float* __restrict__ D1b, float* __restrict__ F1b) {
  const int row = blockIdx.x;
  const int y = blockIdx.y;
  const int lm = y * 2, rm = y * 2 + 1;
  const float* Da = y ? D1a : D0a;
  const float* Fa = y ? F1a : F0a;
  __shared__ __align__(16) float acc[1024];
  __shared__ int lcol[112];
  __shared__ float lw[112];
  __shared__ int cl;
  __shared__ float red[4];
  __shared__ float sdiag;
  ((float4*)acc)[threadIdx.x] = make_float4(0.f, 0.f, 0.f, 0.f);
  const float di = Da[row];
  const int cnt_l = gcnt[(size_t)lm * 1024 + row];
  const size_t lb = ((size_t)lm * 1024 + row) * CSR_STRIDE;
  if (threadIdx.x < cnt_l) {
    int k = gcol[lb + threadIdx.x];
    lcol[threadIdx.x] = k;
    lw[threadIdx.x] = di * gval[lb + threadIdx.x] * Da[k];
  }
  if (threadIdx.x == 0) {
    int c = cnt_l;
    if (Fa[row] != 0.f) { lcol[c] = row; lw[c] = di * di; ++c; }
    cl = c;
  }
  __syncthreads();
  const int wid = threadIdx.x >> 6, lane = threadIdx.x & 63;
  const int cle = cl;
  for (int e = wid; e < cle; e += 4) {
    const int k = lcol[e];
    const float w = lw[e];
    const size_t rbv = ((size_t)rm * 1024 + k) * CSR_STRIDE;
    const int rc = gcnt[(size_t)rm * 1024 + k];
    for (int t = lane; t < rc; t += 64)
      atomicAdd(&acc[gcol[rbv + t]], w * gval[rbv + t]);
  }
  __syncthreads();
  float4 o = ((const float4*)acc)[threadIdx.x];
  float* C = y ? BT : M0;
  ((float4*)(C + (size_t)row * N))[threadIdx.x] = o;
  if (threadIdx.x == (row >> 2)) sdiag = ((const float*)&o)[row & 3];
  float s = o.x + o.y + o.z + o.w;
  #pragma unroll
  for (int off = 32; off > 0; off >>= 1) s += __shfl_down(s, off, 64);
  if ((threadIdx.x & 63) == 0) red[threadIdx.x >> 6] = s;
  __syncthreads();
  if (threadIdx.x == 0) {
    float tot = red[0] + red[1] + red[2] + red[3];
    float fl = (sdiag == 0.f) ? 1.f : 0.f;
    float deg = tot + fl;
    float* D = y ? D1b : D0b;
    float* F = y ? F1b : F0b;
    D[row] = (deg > 0.f) ? (1.f / sqrtf(deg)) : 0.f;
    F[row] = fl;
  }
}

// ---------------- 128x128 tile, 8x8/thread dense matmul with fused left-normalization ----------------
__device__ __forceinline__ void mm_body128(const float* __restrict__ A,
    const float* __restrict__ dinv, const float* __restrict__ dflg,
    const float* __restrict__ B, float* __restrict__ C, int kbase, int klen) {
  __shared__ float As[16][132];
  __shared__ float Bs[16][128];
  const int tid = threadIdx.x;
  const int tx = tid & 15, ty = tid >> 4;
  const int bm = blockIdx.y << 7, bn = blockIdx.x << 7;
  const int ar = tid >> 2;
  const int ac = (tid & 3) << 2;
  const int br = tid >> 5;
  const int bc = (tid & 31) << 2;
  const int ai0 = bm + ar, ai1 = ai0 + 64;
  const float di0 = dinv[ai0], fl0 = dflg[ai0];
  const float di1 = dinv[ai1], fl1 = dflg[ai1];
  float acc[8][8];
  #pragma unroll
  for (int i = 0; i < 8; ++i)
    #pragma unroll
    for (int j = 0; j < 8; ++j) acc[i][j] = 0.f;

  auto loadA = [&](int row, float di, float fl, int kg) -> float4 {
    float4 v = *(const float4*)&A[(size_t)row * N + kg];
    const float4 dk = *(const float4*)&dinv[kg];
    int d = row - kg;
    if ((unsigned)d < 4u) ((float*)&v)[d] += fl;
    v.x *= di * dk.x; v.y *= di * dk.y; v.z *= di * dk.z; v.w *= di * dk.w;
    return v;
  };
  float4 av0 = loadA(ai0, di0, fl0, kbase + ac);
  float4 av1 = loadA(ai1, di1, fl1, kbase + ac);
  float4 bv0 = *(const float4*)&B[(size_t)(kbase + br) * N + bn + bc];
  float4 bv1 = *(const float4*)&B[(size_t)(kbase + br + 8) * N + bn + bc];
  for (int k0 = 0; k0 < klen; k0 += 16) {
    __syncthreads();
    As[ac + 0][ar] = av0.x; As[ac + 1][ar] = av0.y; As[ac + 2][ar] = av0.z; As[ac + 3][ar] = av0.w;
    As[ac + 0][ar + 64] = av1.x; As[ac + 1][ar + 64] = av1.y; As[ac + 2][ar + 64] = av1.z; As[ac + 3][ar + 64] = av1.w;
    *(float4*)&Bs[br][bc] = bv0;
    *(float4*)&Bs[br + 8][bc] = bv1;
    __syncthreads();
    if (k0 + 16 < klen) {
      int kg = kbase + k0 + 16;
      av0 = loadA(ai0, di0, fl0, kg + ac);
      av1 = loadA(ai1, di1, fl1, kg + ac);
      bv0 = *(const float4*)&B[(size_t)(kg + br) * N + bn + bc];
      bv1 = *(const float4*)&B[(size_t)(kg + br + 8) * N + bn + bc];
    }
    #pragma unroll
    for (int kk = 0; kk < 16; ++kk) {
      float4 a0 = *(const float4*)&As[kk][ty << 2];
      float4 a1 = *(const float4*)&As[kk][64 + (ty << 2)];
      float4 b0 = *(const float4*)&Bs[kk][tx << 2];
      float4 b1 = *(const float4*)&Bs[kk][64 + (tx << 2)];
      float av[8] = {a0.x, a0.y, a0.z, a0.w, a1.x, a1.y, a1.z, a1.w};
      float bv[8] = {b0.x, b0.y, b0.z, b0.w, b1.x, b1.y, b1.z, b1.w};
      #pragma unroll
      for (int i = 0; i < 8; ++i)
        #pragma unroll
        for (int j = 0; j < 8; ++j)
          acc[i][j] = fmaf(av[i], bv[j], acc[i][j]);
    }
  }
  #pragma unroll
  for (int i = 0; i < 8; ++i) {
    int row = bm + ((i < 4) ? ((ty << 2) + i) : (64 + (ty << 2) + i - 4));
    *(float4*)&C[(size_t)row * N + bn + (tx << 2)] =
        make_float4(acc[i][0], acc[i][1], acc[i][2], acc[i][3]);
    *(float4*)&C[(size_t)row * N + bn + 64 + (tx << 2)] =
        make_float4(acc[i][4], acc[i][5], acc[i][6], acc[i][7]);
  }
}

// single matmul, split-K=4; partials z<3 -> Pa+z*NN, z==3 -> Pb
__global__ __launch_bounds__(256) void k_mm4(
    const float* __restrict__ A, const float* __restrict__ d, const float* __restrict__ f,
    const float* __restrict__ B, float* __restrict__ Pa, float* __restrict__ Pb) {
  const int z = blockIdx.z;
  float* dst = (z < 3) ? (Pa + (size_t)z * NN) : Pb;
  mm_body128(A, d, f, B, dst, z * 256, 256);
}

// ---------------- sum 4 partials (Pa x3 + Pb) + deg; dst = Pa ----------------
__global__ __launch_bounds__(256) void k_sumdeg4(float* __restrict__ Pa, const float* __restrict__ Pb,
    float* __restrict__ D1, float* __restrict__ F1) {
  const int row = blockIdx.x;
  const int j = threadIdx.x;
  float4 o = make_float4(0.f, 0.f, 0.f, 0.f);
  #pragma unroll
  for (int t = 0; t < 3; ++t) {
    float4 a = ((const float4*)(Pa + (size_t)t * NN + (size_t)row * N))[j];
    o.x += a.x; o.y += a.y; o.z += a.z; o.w += a.w;
  }
  {
    float4 a = ((const float4*)(Pb + (size_t)row * N))[j];
    o.x += a.x; o.y += a.y; o.z += a.z; o.w += a.w;
  }
  ((float4*)(Pa + (size_t)row * N))[j] = o;
  __shared__ float sdiag;
  int d = row - 4 * j;
  if ((unsigned)d < 4u) sdiag = ((float*)&o)[d];
  float s = o.x + o.y + o.z + o.w;
  #pragma unroll
  for (int off = 32; off > 0; off >>= 1) s += __shfl_down(s, off, 64);
  __shared__ float red[4];
  if ((j & 63) == 0) red[j >> 6] = s;
  __syncthreads();
  if (j == 0) {
    float tot = red[0] + red[1] + red[2] + red[3];
    float fl = (sdiag == 0.0f) ? 1.0f : 0.0f;
    float deg = tot + fl;
    D1[row] = (deg > 0.0f) ? (1.0f / sqrtf(deg)) : 0.0f;
    F1[row] = fl;
  }
}

// ---------------- fused max(scale0(M0), scale1(M1)) + deg of result ----------------
__global__ __launch_bounds__(256) void k_maxdeg(const float* __restrict__ M0,
    const float* __restrict__ d0, const float* __restrict__ f0,
    const float* __restrict__ M1, const float* __restrict__ d1, const float* __restrict__ f1,
    float* __restrict__ Aout, float* __restrict__ dinv2, float* __restrict__ dflg2) {
  const int row = blockIdx.x;
  const int j4 = threadIdx.x;
  const float r0 = d0[row], r1 = d1[row];
  const float fl0 = f0[row], fl1 = f1[row];
  float4 a = ((const float4*)(M0 + (size_t)row * N))[j4];
  float4 b = ((const float4*)(M1 + (size_t)row * N))[j4];
  const float4 c0 = ((const float4*)d0)[j4];
  const float4 c1 = ((const float4*)d1)[j4];
  int d = row - 4 * j4;
  if ((unsigned)d < 4u) { ((float*)&a)[d] += fl0; ((float*)&b)[d] += fl1; }
  float4 o;
  o.x = fmaxf(a.x * r0 * c0.x, b.x * r1 * c1.x);
  o.y = fmaxf(a.y * r0 * c0.y, b.y * r1 * c1.y);
  o.z = fmaxf(a.z * r0 * c0.z, b.z * r1 * c1.z);
  o.w = fmaxf(a.w * r0 * c0.w, b.w * r1 * c1.w);
  ((float4*)(Aout + (size_t)row * N))[j4] = o;
  __shared__ float sdiag;
  if ((unsigned)d < 4u) sdiag = ((float*)&o)[d];
  float s = o.x + o.y + o.z + o.w;
  #pragma unroll
  for (int off = 32; off > 0; off >>= 1) s += __shfl_down(s, off, 64);
  __shared__ float red[4];
  if ((threadIdx.x & 63) == 0) red[threadIdx.x >> 6] = s;
  __syncthreads();
  if (threadIdx.x == 0) {
    float tot = red[0] + red[1] + red[2] + red[3];
    float fl = (sdiag == 0.0f) ? 1.0f : 0.0f;
    float deg = tot + fl;
    dinv2[row] = (deg > 0.0f) ? (1.0f / sqrtf(deg)) : 0.0f;
    dflg2[row] = fl;
  }
}

// ---------------- skinny matmul: out = A @ B (+bias)(+relu) ----------------
template<int K, int NCOL, bool BIAS, bool RELU>
__global__ void k_mm_small(const float* __restrict__ A, const float* __restrict__ B,
                           const float* __restrict__ bias, float* __restrict__ out) {
  const int j = threadIdx.x;
  const int i = blockIdx.x * blockDim.y + threadIdx.y;
  const float* ar = A + (size_t)i * K;
  float acc = 0.f;
  #pragma unroll 8
  for (int k = 0; k < K; ++k) acc = fmaf(ar[k], B[(size_t)k * NCOL + j], acc);
  if (BIAS) acc += bias[j];
  if (RELU) acc = fmaxf(acc, 0.f);
  out[(size_t)i * NCOL + j] = acc;
}

// ---------------- skinny matmul with fused An normalization ----------------
template<int NCOL, bool RELU>
__global__ void k_an_mm(const float* __restrict__ BT, const float* __restrict__ dinv,
                        const float* __restrict__ dflg, const float* __restrict__ Bm,
                        const float* __restrict__ bias, float* __restrict__ out) {
  const int j = threadIdx.x;
  const int i = blockIdx.x * blockDim.y + threadIdx.y;
  const float di = dinv[i];
  const float* ar = BT + (size_t)i * N;
  float acc = 0.f;
  for (int k = 0; k < N; k += 4) {
    float4 a4 = *(const float4*)&ar[k];
    float4 d4 = *(const float4*)&dinv[k];
    acc = fmaf(a4.x * d4.x, Bm[(size_t)(k + 0) * NCOL + j], acc);
    acc = fmaf(a4.y * d4.y, Bm[(size_t)(k + 1) * NCOL + j], acc);
    acc = fmaf(a4.z * d4.z, Bm[(size_t)(k + 2) * NCOL + j], acc);
    acc = fmaf(a4.w * d4.w, Bm[(size_t)(k + 3) * NCOL + j], acc);
  }
  acc = fmaf(dflg[i] * dinv[i], Bm[(size_t)i * NCOL + j], acc);
  acc = fmaf(di, acc, bias[j]);
  if (RELU) acc = fmaxf(acc, 0.f);
  out[(size_t)i * NCOL + j] = acc;
}

// ---------------- launcher ----------------
extern "C" void kernel_launch(void* const* d_in, const int* in_sizes, int n_in,
                              void* d_out, int out_size, void* d_ws, size_t ws_size,
                              hipStream_t stream) {
  const float* x     = (const float*)d_in[0];
  const float* w1    = (const float*)d_in[22];
  const float* bias1 = (const float*)d_in[23];
  const float* w2    = (const float*)d_in[24];
  const float* bias2 = (const float*)d_in[25];
  float* out = (float*)d_out;
  float* ws  = (float*)d_ws;

  float* A    = ws + OFF_A;
  float* H1   = ws + OFF_H10;
  float* M0   = ws + OFF_M0;
  float* Pb   = ws + OFF_PB;
  float* BT   = ws + OFF_BT;
  float* Pa   = ws + OFF_PA;
  float* M1   = ws + OFF_M1;
  float* AN   = ws + OFF_AN;
  float* H2_0 = ws + OFF_H20;
  float* H2_1 = ws + OFF_H21;
  int*   gcol = (int*)(ws + OFF_CSR);
  float* gval = ws + OFF_CSR + 4 * 1024 * CSR_STRIDE;
  int*   gcnt = (int*)(ws + OFF_CSR + 8 * 1024 * CSR_STRIDE);
  float* SC   = ws + OFF_SC;
  float *D0a = SC + SC_D0a, *F0a = SC + SC_F0a, *D1a = SC + SC_D1a, *F1a = SC + SC_F1a;
  float *D0b = SC + SC_D0b, *F0b = SC + SC_F0b, *D1b = SC + SC_D1b, *F1b = SC + SC_F1b;
  float *D1c = SC + SC_D1c, *F1c = SC + SC_F1c, *D2 = SC + SC_D2, *F2 = SC + SC_F2;
  float* XW1 = ws + OFF_XW1;
  float* HB  = ws + OFF_HB;
  float* HW2 = ws + OFF_HW2;

  hipMemsetAsync(A, 0, (size_t)5 * NN * sizeof(float), stream);

  dim3 b256(256), b16(16, 16);
  // independent: x @ w1
  k_mm_small<128, 64, false, false><<<256, dim3(64, 4), 0, stream>>>(x, w1, nullptr, XW1);

  k_scatter5<<<640, b256, 0, stream>>>((const int*)d_in[1], (const int*)d_in[2],
                                       (const int*)d_in[3], (const int*)d_in[4],
                                       (const int*)d_in[5], A);

  // attention encoders, both blocks batched per stage
  k_conv1_both<<<dim3(32, 32, 2), b16, 0, stream>>>(A,
      (const float*)d_in[6], (const float*)d_in[7],
      (const float*)d_in[14], (const float*)d_in[15], H1);
  k_conv2_both<<<dim3(17, 17, 2), b16, 0, stream>>>(H1,
      (const float*)d_in[8], (const float*)d_in[9],
      (const float*)d_in[16], (const float*)d_in[17], H2_0, H2_1);
  k_tc_both<<<dim3(32, 32, 2), b16, 0, stream>>>(H2_0, H2_1,
      (const float*)d_in[10], (const float*)d_in[11],
      (const float*)d_in[12], (const float*)d_in[13],
      (const float*)d_in[18], (const float*)d_in[19],
      (const float*)d_in[20], (const float*)d_in[21], A);

  // CSR extraction of A00,A01,A10,A11 + deg of A00/A10
  k_extract<<<dim3(1024, 4), b256, 0, stream>>>(A, gcol, gval, gcnt, D0a, F0a, D1a, F1a);

  // first-hop products via double-sparse SpMM (+ deg epilogues)
  k_spmm<<<dim3(1024, 2), b256, 0, stream>>>(gcol, gval, gcnt,
      D0a, F0a, D1a, F1a, M0, BT, D0b, F0b, D1b, F1b);

  // path1 hop-2 dense matmul, split-K=4
  k_mm4<<<dim3(8, 8, 4), b256, 0, stream>>>(BT, D1b, F1b, A + 4 * NN, Pa, Pb);
  k_sumdeg4<<<1024, b256, 0, stream>>>(Pa, Pb, D1c, F1c);

  // combine + final deg
  k_maxdeg<<<1024, b256, 0, stream>>>(M0, D0b, F0b, M1, D1c, F1c, AN, D2, F2);

  // GCN layers (An normalization fused)
  k_an_mm<64, true><<<256, dim3(64, 4), 0, stream>>>(AN, D2, F2, XW1, bias1, HB);
  k_mm_small<64, 32, false, false><<<128, dim3(32, 8), 0, stream>>>(HB, w2, nullptr, HW2);
  k_an_mm<32, false><<<128, dim3(32, 8), 0, stream>>>(AN, D2, F2, HW2, bias2, out);
}

// Round 8
// 379.986 us; speedup vs baseline: 1.1668x; 1.1668x over previous
//
#include <hip/hip_runtime.h>
#include <math.h>

#define N 1024
#define NN (N*N)
#define NE 32768

// ---------------- workspace layout (floats) ----------------
#define OFF_A    ((size_t)0)
#define OFF_H10  ((size_t)(5*NN))
#define OFF_M0   ((size_t)(5*NN))
#define OFF_CSR  ((size_t)(7*NN))
#define OFF_BT   ((size_t)(9*NN))
#define OFF_M1   ((size_t)(10*NN))
#define OFF_AN   ((size_t)(11*NN))
#define OFF_H20  ((size_t)(13*NN))
#define OFF_H21  (OFF_H20 + 264196)
#define OFF_SC   (OFF_H21 + 264196)
// scalar vectors (1024 each)
#define SC_D0a 0
#define SC_F0a 1024
#define SC_D1a 2048
#define SC_F1a 3072
#define SC_D0b 4096
#define SC_F0b 5120
#define SC_D1b 6144
#define SC_F1b 7168
#define SC_D1c 8192
#define SC_F1c 9216
#define SC_D2  10240
#define SC_F2  11264
#define OFF_XW1  (OFF_SC + 12288)
#define OFF_HB   (OFF_XW1 + 65536)
#define OFF_HW2  (OFF_HB + 65536)

#define CSR_STRIDE 96
#define CSRF (1024 * CSR_STRIDE)
#define CSC_MAXT 80

// ---------------- edge scatter (all 5 edge sets, one launch) ----------------
__global__ void k_scatter5(const int* __restrict__ e0, const int* __restrict__ e1,
                           const int* __restrict__ e2, const int* __restrict__ e3,
                           const int* __restrict__ e4, float* __restrict__ A) {
  int g = blockIdx.x * 256 + threadIdx.x;
  int seg = g >> 15;
  int k = g & 32767;
  const int* e = (seg == 0) ? e0 : (seg == 1) ? e1 : (seg == 2) ? e2 : (seg == 3) ? e3 : e4;
  atomicAdd(&A[(size_t)seg * NN + (size_t)e[k] * N + e[NE + k]], 1.0f);
}

// ---------------- conv1 (pad=1) + relu + maxpool2, both blocks in one dispatch ----------------
template<int L>
__device__ __forceinline__ void conv1_body(const float* __restrict__ A,
    const float* __restrict__ W, const float* __restrict__ Bn, float* __restrict__ out) {
  __shared__ float sIn[L][34][35];
  __shared__ float sW[16 * L * 9];
  __shared__ float sB[16];
  int tid = threadIdx.y * 16 + threadIdx.x;
  for (int i = tid; i < 16 * L * 9; i += 256) sW[i] = W[i];
  if (tid < 16) sB[tid] = Bn[tid];
  const int x0 = blockIdx.x * 32 - 1;
  const int y0 = blockIdx.y * 32 - 1;
  for (int idx = tid; idx < L * 34 * 34; idx += 256) {
    int l = idx / (34 * 34);
    int rem = idx - l * 34 * 34;
    int r = rem / 34, c = rem - r * 34;
    int iy = y0 + r, ix = x0 + c;
    sIn[l][r][c] = (iy >= 0 && iy < N && ix >= 0 && ix < N) ? A[(size_t)l * NN + (size_t)iy * N + ix] : 0.f;
  }
  __syncthreads();
  const int tx = threadIdx.x, ty = threadIdx.y;
  float p[L][4][4];
  #pragma unroll
  for (int l = 0; l < L; ++l)
    #pragma unroll
    for (int r = 0; r < 4; ++r)
      #pragma unroll
      for (int c = 0; c < 4; ++c)
        p[l][r][c] = sIn[l][2 * ty + r][2 * tx + c];
  const int ox = blockIdx.x * 16 + tx;
  const int oy = blockIdx.y * 16 + ty;
  for (int oc = 0; oc < 16; ++oc) {
    float wr[L * 9];
    #pragma unroll
    for (int t = 0; t < L * 9; ++t) wr[t] = sW[oc * L * 9 + t];
    float m = -1e30f;
    #pragma unroll
    for (int dy = 0; dy < 2; ++dy)
      #pragma unroll
      for (int dx = 0; dx < 2; ++dx) {
        float s = 0.f;
        #pragma unroll
        for (int l = 0; l < L; ++l)
          #pragma unroll
          for (int ky = 0; ky < 3; ++ky)
            #pragma unroll
            for (int kx = 0; kx < 3; ++kx)
              s = fmaf(p[l][dy + ky][dx + kx], wr[l * 9 + ky * 3 + kx], s);
        m = fmaxf(m, s);
      }
    out[(size_t)oc * 512 * 512 + (size_t)oy * 512 + ox] = fmaxf(m + sB[oc], 0.f);
  }
}

__global__ __launch_bounds__(256) void k_conv1_both(const float* __restrict__ Ab,
    const float* __restrict__ W0, const float* __restrict__ b0,
    const float* __restrict__ W1, const float* __restrict__ b1, float* __restrict__ H1b) {
  if (blockIdx.z == 0) conv1_body<2>(Ab, W0, b0, H1b);
  else                 conv1_body<3>(Ab + 2 * NN, W1, b1, H1b + 4 * NN);
}

// ---------------- conv2 (pad=2) + relu + maxpool2, both blocks, double-buffered staging ----------------
__global__ __launch_bounds__(256) void k_conv2_both(const float* __restrict__ H1b,
    const float* __restrict__ W0, const float* __restrict__ b0,
    const float* __restrict__ W1, const float* __restrict__ b1,
    float* __restrict__ H2_0, float* __restrict__ H2_1) {
  const int z = blockIdx.z;
  const float* in = H1b + (size_t)z * 4 * NN;
  const float* W  = z ? W1 : W0;
  const float* Bn = z ? b1 : b0;
  float* out = z ? H2_1 : H2_0;
  __shared__ float sIn[2][4][36][37];
  __shared__ float sW[4 * 16 * 9];
  __shared__ float sB[4];
  int tid = threadIdx.y * 16 + threadIdx.x;
  for (int i = tid; i < 4 * 16 * 9; i += 256) sW[i] = W[i];
  if (tid < 4) sB[tid] = Bn[tid];
  const int x0 = blockIdx.x * 32 - 2;
  const int y0 = blockIdx.y * 32 - 2;
  const int tx = threadIdx.x, ty = threadIdx.y;

  auto stage = [&](int g, int buf) {
    for (int idx = tid; idx < 4 * 36 * 36; idx += 256) {
      int icl = idx / 1296;
      int rem = idx - icl * 1296;
      int r = rem / 36, c = rem - r * 36;
      int iy = y0 + r, ix = x0 + c;
      sIn[buf][icl][r][c] = (iy >= 0 && iy < 512 && ix >= 0 && ix < 512)
                            ? in[(size_t)(4 * g + icl) * 262144 + (size_t)iy * 512 + ix] : 0.f;
    }
  };

  float acc[4][2][2];
  #pragma unroll
  for (int oc = 0; oc < 4; ++oc)
    #pragma unroll
    for (int dy = 0; dy < 2; ++dy)
      #pragma unroll
      for (int dx = 0; dx < 2; ++dx) acc[oc][dy][dx] = 0.f;

  stage(0, 0);
  for (int g = 0; g < 4; ++g) {
    __syncthreads();
    if (g < 3) stage(g + 1, (g + 1) & 1);
    const int buf = g & 1;
    #pragma unroll
    for (int icl = 0; icl < 4; ++icl) {
      float p[4][4];
      #pragma unroll
      for (int r = 0; r < 4; ++r)
        #pragma unroll
        for (int c = 0; c < 4; ++c) p[r][c] = sIn[buf][icl][2 * ty + r][2 * tx + c];
      #pragma unroll
      for (int oc = 0; oc < 4; ++oc)
        #pragma unroll
        for (int ky = 0; ky < 3; ++ky)
          #pragma unroll
          for (int kx = 0; kx < 3; ++kx) {
            float w = sW[oc * 144 + (4 * g + icl) * 9 + ky * 3 + kx];
            #pragma unroll
            for (int dy = 0; dy < 2; ++dy)
              #pragma unroll
              for (int dx = 0; dx < 2; ++dx)
                acc[oc][dy][dx] = fmaf(p[dy + ky][dx + kx], w, acc[oc][dy][dx]);
          }
    }
  }
  const int ox = blockIdx.x * 16 + tx;
  const int oy = blockIdx.y * 16 + ty;
  if (ox < 257 && oy < 257) {
    #pragma unroll
    for (int oc = 0; oc < 4; ++oc) {
      float m = fmaxf(fmaxf(acc[oc][0][0], acc[oc][0][1]), fmaxf(acc[oc][1][0], acc[oc][1][1]));
      out[(size_t)oc * 66049 + (size_t)oy * 257 + ox] = fmaxf(m + sB[oc], 0.f);
    }
  }
}

// ---------------- fused tconv1+relu + tconv2+sigmoid + attended (A *= att), both blocks ----------------
__global__ __launch_bounds__(256) void k_tc_both(
    const float* __restrict__ H2_0, const float* __restrict__ H2_1,
    const float* __restrict__ t1w0, const float* __restrict__ t1b0,
    const float* __restrict__ t2w0, const float* __restrict__ t2b0,
    const float* __restrict__ t1w1, const float* __restrict__ t1b1,
    const float* __restrict__ t2w1, const float* __restrict__ t2b1,
    float* __restrict__ Ab) {
  const int z = blockIdx.z;
  const int L = 2 + z;
  const float* in  = z ? H2_1 : H2_0;
  const float* W1p = z ? t1w1 : t1w0;
  const float* B1p = z ? t1b1 : t1b0;
  const float* W2p = z ? t2w1 : t2w0;
  const float* B2p = z ? t2b1 : t2b0;
  float* A = Ab + (size_t)z * 2 * NN;
  __shared__ float sW1[256], sB1[16], sW2[192], sB2[3];
  int tid = threadIdx.y * 16 + threadIdx.x;
  sW1[tid] = W1p[tid];
  if (tid < 16) sB1[tid] = B1p[tid];
  for (int i = tid; i < L * 64; i += 256) sW2[i] = W2p[i];
  if (tid < L) sB2[tid] = B2p[tid];
  __syncthreads();
  const int n = blockIdx.x * 16 + threadIdx.x;   // 0..511
  const int m = blockIdx.y * 16 + threadIdx.y;   // 0..511
  const int p = m >> 1, q = n >> 1;
  const int f1y = 1 - (m & 1), f1x = 1 - (n & 1);
  float vin[4];
  #pragma unroll
  for (int ci = 0; ci < 4; ++ci) vin[ci] = in[(size_t)ci * 66049 + (size_t)p * 257 + q];
  float v[16];
  #pragma unroll
  for (int c = 0; c < 16; ++c) {
    float s = sB1[c];
    #pragma unroll
    for (int ci = 0; ci < 4; ++ci)
      s = fmaf(vin[ci], sW1[c * 16 + ci * 4 + f1y * 2 + f1x], s);
    v[c] = fmaxf(s, 0.f);
  }
  for (int l = 0; l < L; ++l) {
    #pragma unroll
    for (int dy = 0; dy < 2; ++dy)
      #pragma unroll
      for (int dx = 0; dx < 2; ++dx) {
        float s = sB2[l];
        #pragma unroll
        for (int c = 0; c < 16; ++c)
          s = fmaf(v[c], sW2[l * 64 + c * 4 + (1 - dy) * 2 + (1 - dx)], s);
        float sg = 1.f / (1.f + expf(-s));
        size_t idx = (size_t)l * NN + (size_t)(2 * m + dy) * N + (2 * n + dx);
        A[idx] *= sg;
      }
  }
}

// ---------------- extract: CSR of y=0..3, entry-major CSC of y=4 (A12); deg of y=0,2 ----------------
__global__ __launch_bounds__(256) void k_extract(const float* __restrict__ Ab,
    int* __restrict__ gcol, float* __restrict__ gval, int* __restrict__ gcnt,
    int* __restrict__ crowT, float* __restrict__ cvalT, int* __restrict__ ccnt,
    float* __restrict__ D0a, float* __restrict__ F0a,
    float* __restrict__ D1a, float* __restrict__ F1a) {
  const int row = blockIdx.x;
  const int y = blockIdx.y;                 // 0:A00 1:A01 2:A10 3:A11 4:A12
  const float* base = Ab + (size_t)y * NN + (size_t)row * N;
  __shared__ int cnt;
  __shared__ float sdiag;
  __shared__ float red[4];
  if (threadIdx.x == 0) cnt = 0;
  __syncthreads();
  const int j4 = threadIdx.x;
  float4 v = ((const float4*)base)[j4];
  if (j4 == (row >> 2)) sdiag = ((const float*)&v)[row & 3];
  if (y == 4) {
    // entry-major CSC scatter: csc[t*1024 + col]
    #pragma unroll
    for (int t = 0; t < 4; ++t) {
      float x = ((const float*)&v)[t];
      if (x != 0.f) {
        int j = 4 * j4 + t;
        int p = atomicAdd(&ccnt[j], 1);
        if (p < CSC_MAXT) { crowT[p * 1024 + j] = row; cvalT[p * 1024 + j] = x; }
      }
    }
    return;
  }
  const size_t rb = ((size_t)y * 1024 + row) * CSR_STRIDE;
  #pragma unroll
  for (int t = 0; t < 4; ++t) {
    float x = ((const float*)&v)[t];
    if (x != 0.f) {
      int p = atomicAdd(&cnt, 1);
      if (p < CSR_STRIDE) { gcol[rb + p] = 4 * j4 + t; gval[rb + p] = x; }
    }
  }
  float s = v.x + v.y + v.z + v.w;
  #pragma unroll
  for (int o = 32; o > 0; o >>= 1) s += __shfl_down(s, o, 64);
  if ((threadIdx.x & 63) == 0) red[threadIdx.x >> 6] = s;
  __syncthreads();
  if (threadIdx.x == 0) {
    gcnt[(size_t)y * 1024 + row] = (cnt < CSR_STRIDE) ? cnt : CSR_STRIDE;
    if (y == 0 || y == 2) {
      float tot = red[0] + red[1] + red[2] + red[3];
      float fl = (sdiag == 0.f) ? 1.f : 0.f;
      float deg = tot + fl;
      float* D = (y == 0) ? D0a : D1a;
      float* F = (y == 0) ? F0a : F1a;
      D[row] = (deg > 0.f) ? (1.f / sqrtf(deg)) : 0.f;
      F[row] = fl;
    }
  }
}

// ---------------- hop-1 double-sparse SpMM: C_row = [norm(left)]_row @ right, + deg epilogue ----------------
__global__ __launch_bounds__(256) void k_spmm(
    const int* __restrict__ gcol, const float* __restrict__ gval, const int* __restrict__ gcnt,
    const float* __restrict__ D0a, const float* __restrict__ F0a,
    const float* __restrict__ D1a, const float* __restrict__ F1a,
    float* __restrict__ M0, float* __restrict__ BT,
    float* __restrict__ D0b, float* __restrict__ F0b,
    float* __restrict__ D1b, float* __restrict__ F1b) {
  const int row = blockIdx.x;
  const int y = blockIdx.y;
  const int lm = y * 2, rm = y * 2 + 1;
  const float* Da = y ? D1a : D0a;
  const float* Fa = y ? F1a : F0a;
  __shared__ __align__(16) float acc[1024];
  __shared__ int lcol[112];
  __shared__ float lw[112];
  __shared__ int lrc[112];
  __shared__ int cl;
  __shared__ float red[4];
  __shared__ float sdiag;
  ((float4*)acc)[threadIdx.x] = make_float4(0.f, 0.f, 0.f, 0.f);
  const float di = Da[row];
  const int cnt_l = gcnt[(size_t)lm * 1024 + row];
  const size_t lb = ((size_t)lm * 1024 + row) * CSR_STRIDE;
  if (threadIdx.x < cnt_l) {
    int k = gcol[lb + threadIdx.x];
    lcol[threadIdx.x] = k;
    lw[threadIdx.x] = di * gval[lb + threadIdx.x] * Da[k];
    lrc[threadIdx.x] = gcnt[(size_t)rm * 1024 + k];
  }
  if (threadIdx.x == 0) {
    int c = cnt_l;
    if (Fa[row] != 0.f) {
      lcol[c] = row; lw[c] = di * di; lrc[c] = gcnt[(size_t)rm * 1024 + row]; ++c;
    }
    cl = c;
  }
  __syncthreads();
  const int sub = threadIdx.x >> 5, lane = threadIdx.x & 31;
  const int cle = cl;
  for (int e = sub; e < cle; e += 8) {
    const int k = lcol[e];
    const float w = lw[e];
    const int rc = lrc[e];
    const size_t rbv = ((size_t)rm * 1024 + k) * CSR_STRIDE;
    for (int t = lane; t < rc; t += 32)
      atomicAdd(&acc[gcol[rbv + t]], w * gval[rbv + t]);
  }
  __syncthreads();
  float4 o = ((const float4*)acc)[threadIdx.x];
  float* C = y ? BT : M0;
  ((float4*)(C + (size_t)row * N))[threadIdx.x] = o;
  if (threadIdx.x == (row >> 2)) sdiag = ((const float*)&o)[row & 3];
  float s = o.x + o.y + o.z + o.w;
  #pragma unroll
  for (int off = 32; off > 0; off >>= 1) s += __shfl_down(s, off, 64);
  if ((threadIdx.x & 63) == 0) red[threadIdx.x >> 6] = s;
  __syncthreads();
  if (threadIdx.x == 0) {
    float tot = red[0] + red[1] + red[2] + red[3];
    float fl = (sdiag == 0.f) ? 1.f : 0.f;
    float deg = tot + fl;
    float* D = y ? D1b : D0b;
    float* F = y ? F1b : F0b;
    D[row] = (deg > 0.f) ? (1.f / sqrtf(deg)) : 0.f;
    F[row] = fl;
  }
}

// ---------------- hop-2: M1_row = D1b[row] * (btn_row gathered through CSC of A12), + deg ----------------
__global__ __launch_bounds__(256) void k_spmm2(const float* __restrict__ BT,
    const float* __restrict__ D1b, const float* __restrict__ F1b,
    const int* __restrict__ crowT, const float* __restrict__ cvalT, const int* __restrict__ ccnt,
    float* __restrict__ M1, float* __restrict__ D1c, float* __restrict__ F1c) {
  const int row = blockIdx.x;
  __shared__ __align__(16) float bt[1024];
  __shared__ float red[4];
  __shared__ float sdiag;
  const int tid = threadIdx.x;
  {
    float4 b = ((const float4*)(BT + (size_t)row * N))[tid];
    float4 d = ((const float4*)D1b)[tid];
    ((float4*)bt)[tid] = make_float4(b.x * d.x, b.y * d.y, b.z * d.z, b.w * d.w);
  }
  __syncthreads();
  if (tid == 0) bt[row] += F1b[row] * D1b[row];
  __syncthreads();
  const int j0 = tid << 2;
  int4 cn = *(const int4*)&ccnt[j0];
  cn.x = min(cn.x, CSC_MAXT); cn.y = min(cn.y, CSC_MAXT);
  cn.z = min(cn.z, CSC_MAXT); cn.w = min(cn.w, CSC_MAXT);
  const int tmax = max(max(cn.x, cn.y), max(cn.z, cn.w));
  float4 o = make_float4(0.f, 0.f, 0.f, 0.f);
  for (int t = 0; t < tmax; ++t) {
    const int4   r = *(const int4*)&crowT[t * 1024 + j0];
    const float4 v = *(const float4*)&cvalT[t * 1024 + j0];
    if (t < cn.x) o.x = fmaf(bt[r.x], v.x, o.x);
    if (t < cn.y) o.y = fmaf(bt[r.y], v.y, o.y);
    if (t < cn.z) o.z = fmaf(bt[r.z], v.z, o.z);
    if (t < cn.w) o.w = fmaf(bt[r.w], v.w, o.w);
  }
  const float dr = D1b[row];
  o.x *= dr; o.y *= dr; o.z *= dr; o.w *= dr;
  ((float4*)(M1 + (size_t)row * N))[tid] = o;
  if (tid == (row >> 2)) sdiag = ((const float*)&o)[row & 3];
  float s = o.x + o.y + o.z + o.w;
  #pragma unroll
  for (int off = 32; off > 0; off >>= 1) s += __shfl_down(s, off, 64);
  if ((tid & 63) == 0) red[tid >> 6] = s;
  __syncthreads();
  if (tid == 0) {
    float tot = red[0] + red[1] + red[2] + red[3];
    float fl = (sdiag == 0.f) ? 1.f : 0.f;
    float deg = tot + fl;
    D1c[row] = (deg > 0.f) ? (1.f / sqrtf(deg)) : 0.f;
    F1c[row] = fl;
  }
}

// ---------------- fused max(scale0(M0), scale1(M1)) + deg of result ----------------
__global__ __launch_bounds__(256) void k_maxdeg(const float* __restrict__ M0,
    const float* __restrict__ d0, const float* __restrict__ f0,
    const float* __restrict__ M1, const float* __restrict__ d1, const float* __restrict__ f1,
    float* __restrict__ Aout, float* __restrict__ dinv2, float* __restrict__ dflg2) {
  const int row = blockIdx.x;
  const int j4 = threadIdx.x;
  const float r0 = d0[row], r1 = d1[row];
  const float fl0 = f0[row], fl1 = f1[row];
  float4 a = ((const float4*)(M0 + (size_t)row * N))[j4];
  float4 b = ((const float4*)(M1 + (size_t)row * N))[j4];
  const float4 c0 = ((const float4*)d0)[j4];
  const float4 c1 = ((const float4*)d1)[j4];
  int d = row - 4 * j4;
  if ((unsigned)d < 4u) { ((float*)&a)[d] += fl0; ((float*)&b)[d] += fl1; }
  float4 o;
  o.x = fmaxf(a.x * r0 * c0.x, b.x * r1 * c1.x);
  o.y = fmaxf(a.y * r0 * c0.y, b.y * r1 * c1.y);
  o.z = fmaxf(a.z * r0 * c0.z, b.z * r1 * c1.z);
  o.w = fmaxf(a.w * r0 * c0.w, b.w * r1 * c1.w);
  ((float4*)(Aout + (size_t)row * N))[j4] = o;
  __shared__ float sdiag;
  if ((unsigned)d < 4u) sdiag = ((float*)&o)[d];
  float s = o.x + o.y + o.z + o.w;
  #pragma unroll
  for (int off = 32; off > 0; off >>= 1) s += __shfl_down(s, off, 64);
  __shared__ float red[4];
  if ((threadIdx.x & 63) == 0) red[threadIdx.x >> 6] = s;
  __syncthreads();
  if (threadIdx.x == 0) {
    float tot = red[0] + red[1] + red[2] + red[3];
    float fl = (sdiag == 0.0f) ? 1.0f : 0.0f;
    float deg = tot + fl;
    dinv2[row] = (deg > 0.0f) ? (1.0f / sqrtf(deg)) : 0.0f;
    dflg2[row] = fl;
  }
}

// ---------------- skinny matmul: out = A @ B (+bias)(+relu) ----------------
template<int K, int NCOL, bool BIAS, bool RELU>
__global__ void k_mm_small(const float* __restrict__ A, const float* __restrict__ B,
                           const float* __restrict__ bias, float* __restrict__ out) {
  const int j = threadIdx.x;
  const int i = blockIdx.x * blockDim.y + threadIdx.y;
  const float* ar = A + (size_t)i * K;
  float acc = 0.f;
  #pragma unroll 8
  for (int k = 0; k < K; ++k) acc = fmaf(ar[k], B[(size_t)k * NCOL + j], acc);
  if (BIAS) acc += bias[j];
  if (RELU) acc = fmaxf(acc, 0.f);
  out[(size_t)i * NCOL + j] = acc;
}

// ---------------- skinny matmul with fused An normalization ----------------
template<int NCOL, bool RELU>
__global__ void k_an_mm(const float* __restrict__ BT, const float* __restrict__ dinv,
                        const float* __restrict__ dflg, const float* __restrict__ Bm,
                        const float* __restrict__ bias, float* __restrict__ out) {
  const int j = threadIdx.x;
  const int i = blockIdx.x * blockDim.y + threadIdx.y;
  const float di = dinv[i];
  const float* ar = BT + (size_t)i * N;
  float acc = 0.f;
  for (int k = 0; k < N; k += 4) {
    float4 a4 = *(const float4*)&ar[k];
    float4 d4 = *(const float4*)&dinv[k];
    acc = fmaf(a4.x * d4.x, Bm[(size_t)(k + 0) * NCOL + j], acc);
    acc = fmaf(a4.y * d4.y, Bm[(size_t)(k + 1) * NCOL + j], acc);
    acc = fmaf(a4.z * d4.z, Bm[(size_t)(k + 2) * NCOL + j], acc);
    acc = fmaf(a4.w * d4.w, Bm[(size_t)(k + 3) * NCOL + j], acc);
  }
  acc = fmaf(dflg[i] * dinv[i], Bm[(size_t)i * NCOL + j], acc);
  acc = fmaf(di, acc, bias[j]);
  if (RELU) acc = fmaxf(acc, 0.f);
  out[(size_t)i * NCOL + j] = acc;
}

// ---------------- launcher ----------------
extern "C" void kernel_launch(void* const* d_in, const int* in_sizes, int n_in,
                              void* d_out, int out_size, void* d_ws, size_t ws_size,
                              hipStream_t stream) {
  const float* x     = (const float*)d_in[0];
  const float* w1    = (const float*)d_in[22];
  const float* bias1 = (const float*)d_in[23];
  const float* w2    = (const float*)d_in[24];
  const float* bias2 = (const float*)d_in[25];
  float* out = (float*)d_out;
  float* ws  = (float*)d_ws;

  float* A    = ws + OFF_A;
  float* H1   = ws + OFF_H10;
  float* M0   = ws + OFF_M0;
  float* BT   = ws + OFF_BT;
  float* M1   = ws + OFF_M1;
  float* AN   = ws + OFF_AN;
  float* H2_0 = ws + OFF_H20;
  float* H2_1 = ws + OFF_H21;
  int*   gcol  = (int*)(ws + OFF_CSR);
  float* gval  = ws + OFF_CSR + (size_t)4 * CSRF;
  int*   gcnt  = (int*)(ws + OFF_CSR + (size_t)8 * CSRF);
  int*   crowT = (int*)(ws + OFF_CSR + (size_t)8 * CSRF + 4096);
  float* cvalT = ws + OFF_CSR + (size_t)8 * CSRF + 4096 + CSC_MAXT * 1024;
  int*   ccnt  = (int*)(ws + OFF_CSR + (size_t)8 * CSRF + 4096 + (size_t)2 * CSC_MAXT * 1024);
  float* SC   = ws + OFF_SC;
  float *D0a = SC + SC_D0a, *F0a = SC + SC_F0a, *D1a = SC + SC_D1a, *F1a = SC + SC_F1a;
  float *D0b = SC + SC_D0b, *F0b = SC + SC_F0b, *D1b = SC + SC_D1b, *F1b = SC + SC_F1b;
  float *D1c = SC + SC_D1c, *F1c = SC + SC_F1c, *D2 = SC + SC_D2, *F2 = SC + SC_F2;
  float* XW1 = ws + OFF_XW1;
  float* HB  = ws + OFF_HB;
  float* HW2 = ws + OFF_HW2;

  hipMemsetAsync(A, 0, (size_t)5 * NN * sizeof(float), stream);

  dim3 b256(256), b16(16, 16);
  // independent: x @ w1
  k_mm_small<128, 64, false, false><<<256, dim3(64, 4), 0, stream>>>(x, w1, nullptr, XW1);

  k_scatter5<<<640, b256, 0, stream>>>((const int*)d_in[1], (const int*)d_in[2],
                                       (const int*)d_in[3], (const int*)d_in[4],
                                       (const int*)d_in[5], A);

  // attention encoders, both blocks batched per stage
  k_conv1_both<<<dim3(32, 32, 2), b16, 0, stream>>>(A,
      (const float*)d_in[6], (const float*)d_in[7],
      (const float*)d_in[14], (const float*)d_in[15], H1);
  k_conv2_both<<<dim3(17, 17, 2), b16, 0, stream>>>(H1,
      (const float*)d_in[8], (const float*)d_in[9],
      (const float*)d_in[16], (const float*)d_in[17], H2_0, H2_1);
  k_tc_both<<<dim3(32, 32, 2), b16, 0, stream>>>(H2_0, H2_1,
      (const float*)d_in[10], (const float*)d_in[11],
      (const float*)d_in[12], (const float*)d_in[13],
      (const float*)d_in[18], (const float*)d_in[19],
      (const float*)d_in[20], (const float*)d_in[21], A);

  // ccnt aliases dead-H1 space: zero it only AFTER conv2 has consumed H1
  // (R7 bug: zeroing at stream head let conv1's H1 writes clobber it)
  hipMemsetAsync(ccnt, 0, 1024 * sizeof(int), stream);

  // CSR of A00,A01,A10,A11 + CSC of A12 + deg of A00/A10
  k_extract<<<dim3(1024, 5), b256, 0, stream>>>(A, gcol, gval, gcnt,
      crowT, cvalT, ccnt, D0a, F0a, D1a, F1a);

  // hop-1 products via double-sparse SpMM (+ deg epilogues)
  k_spmm<<<dim3(1024, 2), b256, 0, stream>>>(gcol, gval, gcnt,
      D0a, F0a, D1a, F1a, M0, BT, D0b, F0b, D1b, F1b);

  // hop-2 via LDS-gather against CSC of A12 (+ deg epilogue)
  k_spmm2<<<1024, b256, 0, stream>>>(BT, D1b, F1b, crowT, cvalT, ccnt, M1, D1c, F1c);

  // combine + final deg
  k_maxdeg<<<1024, b256, 0, stream>>>(M0, D0b, F0b, M1, D1c, F1c, AN, D2, F2);

  // GCN layers (An normalization fused)
  k_an_mm<64, true><<<256, dim3(64, 4), 0, stream>>>(AN, D2, F2, XW1, bias1, HB);
  k_mm_small<64, 32, false, false><<<128, dim3(32, 8), 0, stream>>>(HB, w2, nullptr, HW2);
  k_an_mm<32, false><<<128, dim3(32, 8), 0, stream>>>(AN, D2, F2, HW2, bias2, out);
}